// Round 6
// baseline (134.868 us; speedup 1.0000x reference)
//
#include <hip/hip_runtime.h>
#include <hip/hip_cooperative_groups.h>
#include <math.h>

namespace cg = cooperative_groups;

// Problem dims (fixed by reference setup_inputs)
#define B 8
#define NPTS 20000
#define M 1024
#define H 1024
#define BN_EPS 1e-5f

#define NSLAB 32
#define SLABPTS 625              // 32 * 625 = 20000
#define KM 16                    // basis points per thread (lane-major m)

typedef float f2 __attribute__((ext_vector_type(2)));

struct Params {
    const float *x, *basis;
    const float *g1, *bb1, *rm1, *rv1;
    const float *w1, *b1;
    const float *g2, *bb2, *rm2, *rv2;
    const float *w2, *b2;
    float *out;
    float *pmin;   // [NSLAB][B][M]
    float *fsg;    // [B][M]
    float *psum;   // [H][B]
};

// ---------------------------------------------------------------------------
// Single cooperative kernel, grid = 256 blocks x 256 threads.
// A: BPS slab-min (block = (b, slab)); B: 32-slab reduce + bn1; C: MLP;
// D: final sum. grid.sync() between phases (device-scope fence included).
// ---------------------------------------------------------------------------
__global__ __launch_bounds__(256) void fused_kernel(Params p) {
    __shared__ float sxf[626], syf[626], szf[626], swf[626];   // ~10 KB
    __shared__ float smin[4][M];                               // 16 KB
    __shared__ float fsl[B * M];                               // 32 KB
    cg::grid_group grid = cg::this_grid();
    const int bid = blockIdx.x;
    const int tid = threadIdx.x;
    const int lane = tid & 63;
    const int w = tid >> 6;

    // ---------------- Phase A: BPS over one (b, slab) ----------------
    {
        const int b = bid >> 5;            // 0..7
        const int slab = bid & 31;         // 0..31
        const int n0 = slab * SLABPTS;
        const float* xb = p.x + (size_t)b * 3 * NPTS;

        for (int idx = tid; idx < SLABPTS; idx += 256) {
            float px = xb[n0 + idx];
            float py = xb[NPTS + n0 + idx];
            float pz = xb[2 * NPTS + n0 + idx];
            sxf[idx] = px;
            syf[idx] = py;
            szf[idx] = pz;
            swf[idx] = px * px + py * py + pz * pz;
        }

        // 16 basis points per lane: m = lane + 64*i (pre-negated-doubled)
        float nbx[KM], nby[KM], nbz[KM], bb2r[KM], acc[KM];
#pragma unroll
        for (int i = 0; i < KM; ++i) {
            int m = lane + 64 * i;
            float bx = p.basis[m * 3 + 0];
            float by = p.basis[m * 3 + 1];
            float bz = p.basis[m * 3 + 2];
            nbx[i] = -2.0f * bx;
            nby[i] = -2.0f * by;
            nbz[i] = -2.0f * bz;
            bb2r[i] = bx * bx + by * by + bz * bz;
            acc[i] = INFINITY;
        }
        __syncthreads();

        // 312 pairs (624 pts); wave w owns pairs [78w, 78w+78); 2 pairs/iter
        const int j0 = w * 78;
        for (int j = j0; j < j0 + 78; j += 2) {
            float4 X4 = *reinterpret_cast<float4*>(&sxf[2 * j]);
            float4 Y4 = *reinterpret_cast<float4*>(&syf[2 * j]);
            float4 Z4 = *reinterpret_cast<float4*>(&szf[2 * j]);
            float4 W4 = *reinterpret_cast<float4*>(&swf[2 * j]);
            f2 Xa = {X4.x, X4.y}, Xb = {X4.z, X4.w};
            f2 Ya = {Y4.x, Y4.y}, Yb = {Y4.z, Y4.w};
            f2 Za = {Z4.x, Z4.y}, Zb = {Z4.z, Z4.w};
            f2 Wa = {W4.x, W4.y}, Wb = {W4.z, W4.w};
#pragma unroll
            for (int i = 0; i < KM; ++i) {
                f2 s0 = __builtin_elementwise_fma(Xa, (f2){nbx[i], nbx[i]}, Wa);
                s0 = __builtin_elementwise_fma(Ya, (f2){nby[i], nby[i]}, s0);
                s0 = __builtin_elementwise_fma(Za, (f2){nbz[i], nbz[i]}, s0);
                f2 s1 = __builtin_elementwise_fma(Xb, (f2){nbx[i], nbx[i]}, Wb);
                s1 = __builtin_elementwise_fma(Yb, (f2){nby[i], nby[i]}, s1);
                s1 = __builtin_elementwise_fma(Zb, (f2){nbz[i], nbz[i]}, s1);
                acc[i] = fminf(acc[i], fminf(fminf(s0.x, s0.y), fminf(s1.x, s1.y)));
            }
        }
        // leftover point 624 (wave 0 only)
        if (w == 0) {
            float px = sxf[624], py = syf[624], pz = szf[624], pw = swf[624];
#pragma unroll
            for (int i = 0; i < KM; ++i) {
                float s = fmaf(px, nbx[i], pw);
                s = fmaf(py, nby[i], s);
                s = fmaf(pz, nbz[i], s);
                acc[i] = fminf(acc[i], s);
            }
        }

#pragma unroll
        for (int i = 0; i < KM; ++i) smin[w][lane + 64 * i] = acc[i] + bb2r[i];
        __syncthreads();

#pragma unroll
        for (int q = 0; q < 4; ++q) {
            int m = tid + q * 256;
            float v = fminf(fminf(smin[0][m], smin[1][m]), fminf(smin[2][m], smin[3][m]));
            p.pmin[(size_t)slab * (B * M) + b * M + m] = fmaxf(v, 0.0f);
        }
    }
    grid.sync();

    // ---------------- Phase B: 32-slab reduce + bn1 ----------------
    if (bid < 32) {
        int e = bid * 256 + tid;            // 0..8191  (b = e>>10, m = e&1023)
        int m = e & (M - 1);
        float v = INFINITY;
#pragma unroll 8
        for (int s = 0; s < NSLAB; ++s) {
            v = fminf(v, p.pmin[(size_t)s * (B * M) + e]);
        }
        float f = sqrtf(v);
        float sc = p.g1[m] * rsqrtf(p.rv1[m] + BN_EPS);
        p.fsg[e] = (f - p.rm1[m]) * sc + p.bb1[m];
    }
    grid.sync();

    // ---------------- Phase C: MLP (bn1-feat @ w1 + relu + bn2 + w2) -------
    {
        for (int k = tid; k < B * M / 4; k += 256) {
            reinterpret_cast<float4*>(fsl)[k] = reinterpret_cast<const float4*>(p.fsg)[k];
        }
        __syncthreads();

        const int i = bid * 4 + w;          // output row 0..1023
        const float* wrow = p.w1 + (size_t)i * M;
        float hsum[B] = {0, 0, 0, 0, 0, 0, 0, 0};
#pragma unroll
        for (int seg = 0; seg < 4; ++seg) {
            int m0 = seg * 256 + lane * 4;
            float4 wv4 = *reinterpret_cast<const float4*>(wrow + m0);
#pragma unroll
            for (int bb = 0; bb < B; ++bb) {
                float4 fv = *reinterpret_cast<const float4*>(&fsl[bb * M + m0]);
                hsum[bb] = fmaf(fv.x, wv4.x, hsum[bb]);
                hsum[bb] = fmaf(fv.y, wv4.y, hsum[bb]);
                hsum[bb] = fmaf(fv.z, wv4.z, hsum[bb]);
                hsum[bb] = fmaf(fv.w, wv4.w, hsum[bb]);
            }
        }
#pragma unroll
        for (int bb = 0; bb < B; ++bb) {
#pragma unroll
            for (int off = 32; off > 0; off >>= 1) {
                hsum[bb] += __shfl_down(hsum[bb], off, 64);
            }
        }
        if (lane == 0) {
            float b1i = p.b1[i];
            float sc2 = p.g2[i] * rsqrtf(p.rv2[i] + BN_EPS);
            float rm = p.rm2[i];
            float bt = p.bb2[i];
            float w2i = p.w2[i];
#pragma unroll
            for (int bb = 0; bb < B; ++bb) {
                float v = fmaxf(hsum[bb] + b1i, 0.0f);
                v = (v - rm) * sc2 + bt;
                p.psum[(size_t)i * B + bb] = v * w2i;
            }
        }
    }
    grid.sync();

    // ---------------- Phase D: out[b] = b2 + sum_i psum[i][b] ----------------
    if (bid == 0) {
        const int bb = tid >> 5;
        const int sl = tid & 31;
        float s = 0.0f;
        for (int i = sl; i < H; i += 32) {
            s += p.psum[(size_t)i * B + bb];
        }
#pragma unroll
        for (int off = 16; off > 0; off >>= 1) {
            s += __shfl_down(s, off, 32);
        }
        if (sl == 0) {
            p.out[bb] = s + p.b2[0];
        }
    }
}

// ---------------------------------------------------------------------------
extern "C" void kernel_launch(void* const* d_in, const int* in_sizes, int n_in,
                              void* d_out, int out_size, void* d_ws, size_t ws_size,
                              hipStream_t stream) {
    Params prm;
    prm.x     = (const float*)d_in[0];
    prm.basis = (const float*)d_in[1];
    prm.g1    = (const float*)d_in[2];
    prm.bb1   = (const float*)d_in[3];
    prm.rm1   = (const float*)d_in[4];
    prm.rv1   = (const float*)d_in[5];
    prm.w1    = (const float*)d_in[6];
    prm.b1    = (const float*)d_in[7];
    prm.g2    = (const float*)d_in[8];
    prm.bb2   = (const float*)d_in[9];
    prm.rm2   = (const float*)d_in[10];
    prm.rv2   = (const float*)d_in[11];
    prm.w2    = (const float*)d_in[12];
    prm.b2    = (const float*)d_in[13];
    prm.out   = (float*)d_out;

    char* ws = (char*)d_ws;
    prm.pmin = (float*)ws;                                     // 32*8*1024 f = 1 MB
    prm.fsg  = (float*)(ws + (size_t)NSLAB * B * M * 4);       // 8*1024 f
    prm.psum = (float*)(ws + (size_t)NSLAB * B * M * 4 + B * M * 4); // 1024*8 f

    void* args[] = { &prm };
    hipLaunchCooperativeKernel((const void*)fused_kernel, dim3(256), dim3(256),
                               args, 0, stream);
}

// Round 8
// 70.966 us; speedup vs baseline: 1.9005x; 1.9005x over previous
//
#include <hip/hip_runtime.h>
#include <hip/hip_cooperative_groups.h>
#include <math.h>

namespace cg = cooperative_groups;

// Problem dims (fixed by reference setup_inputs)
#define B 8
#define NPTS 20000
#define M 1024
#define H 1024
#define BN_EPS 1e-5f

#define MC 16                    // m per 256-thread sub-block
#define NPAIRS (NPTS / 2)        // 10000

typedef float f2 __attribute__((ext_vector_type(2)));

struct Params {
    const float *x, *basis;
    const float *g1, *bb1, *rm1, *rv1;
    const float *w1, *b1;
    const float *g2, *bb2, *rm2, *rv2;
    const float *w2, *b2;
    float *out;
    float *fsg;    // [B][M] bn1 features
};

// ---------------------------------------------------------------------------
// One cooperative kernel, grid = 256 blocks x 512 threads.
// (Round 7's 512-block coop launch was rejected by the runtime -> silent
//  no-op. 256 blocks is the empirically-proven coop grid; waves come from
//  the 512-thread block instead.)
// Phase A: two 256-thread sub-blocks per block; sub-block handles
//   vbid = bid*2+sub -> (b = vbid>>6, mc = vbid&63): min over ALL 20000
//   points for its 16 m. Basis is sub-block-uniform (SGPRs); acc[16] in
//   VGPRs (16-deep ILP); points streamed coalesced from L2/L3 as float2.
//   Wave shuffle-reduce + tiny LDS combine, fused sqrt+bn1 -> fsg.
// grid.sync()
// Phase C: blocks 0..127, wave w computes the full-M dot for row
//   i = bid*8+w for all 8 batches, shuffle-reduce, bn2+w2 scale, LDS
//   block-partial, 8 atomicAdds into out (seeded with b2 in phase A).
// ---------------------------------------------------------------------------
__global__ __launch_bounds__(512, 2) void fused_kernel(Params p) {
    __shared__ float smin[2][4][MC];
    __shared__ float cpart[8][B];
    cg::grid_group grid = cg::this_grid();
    const int bid = blockIdx.x;
    const int tid = threadIdx.x;
    const int lane = tid & 63;
    const int w = tid >> 6;            // 0..7 (wave in block)
    const int sub = tid >> 8;          // 0..1 (sub-block)
    const int st = tid & 255;          // thread within sub-block
    const int wsub = w & 3;            // wave within sub-block

    // ---------------- Phase A ----------------
    {
        const int vbid = bid * 2 + sub;    // 0..511
        const int b = vbid >> 6;           // 0..7
        const int mc = vbid & 63;          // 0..63
        const int m0 = mc * MC;
        const float* xb = p.x + (size_t)b * 3 * NPTS;

        // 16 sub-block-uniform basis points (scalar loads -> SGPRs)
        float nbx[MC], nby[MC], nbz[MC];
#pragma unroll
        for (int i = 0; i < MC; ++i) {
            int m = m0 + i;
            nbx[i] = -2.0f * p.basis[m * 3 + 0];
            nby[i] = -2.0f * p.basis[m * 3 + 1];
            nbz[i] = -2.0f * p.basis[m * 3 + 2];
        }
        float acc[MC];
#pragma unroll
        for (int i = 0; i < MC; ++i) acc[i] = INFINITY;

        // stream 10000 point-pairs: thread st takes pairs st, st+256, ...
        for (int c = 0; c < 40; ++c) {
            int pi = c * 256 + st;
            if (pi < NPAIRS) {
                f2 X = *reinterpret_cast<const f2*>(xb + 2 * pi);
                f2 Y = *reinterpret_cast<const f2*>(xb + NPTS + 2 * pi);
                f2 Z = *reinterpret_cast<const f2*>(xb + 2 * NPTS + 2 * pi);
                f2 W = X * X;
                W = __builtin_elementwise_fma(Y, Y, W);
                W = __builtin_elementwise_fma(Z, Z, W);
#pragma unroll
                for (int i = 0; i < MC; ++i) {
                    f2 s = __builtin_elementwise_fma(X, (f2){nbx[i], nbx[i]}, W);
                    s = __builtin_elementwise_fma(Y, (f2){nby[i], nby[i]}, s);
                    s = __builtin_elementwise_fma(Z, (f2){nbz[i], nbz[i]}, s);
                    acc[i] = fminf(acc[i], fminf(s.x, s.y));
                }
            }
        }

        // wave min-reduce (16 m x 6 levels)
#pragma unroll
        for (int i = 0; i < MC; ++i) {
#pragma unroll
            for (int off = 32; off > 0; off >>= 1) {
                acc[i] = fminf(acc[i], __shfl_down(acc[i], off, 64));
            }
        }
        if (lane == 0) {
#pragma unroll
            for (int i = 0; i < MC; ++i) smin[sub][wsub][i] = acc[i];
        }
        __syncthreads();

        if (st < MC) {
            int m = m0 + st;
            float v = fminf(fminf(smin[sub][0][st], smin[sub][1][st]),
                            fminf(smin[sub][2][st], smin[sub][3][st]));
            float bx = p.basis[m * 3 + 0];
            float by = p.basis[m * 3 + 1];
            float bz = p.basis[m * 3 + 2];
            v = fmaxf(v + bx * bx + by * by + bz * bz, 0.0f);  // + |b|^2, clip
            float f = sqrtf(v);
            float sc = p.g1[m] * rsqrtf(p.rv1[m] + BN_EPS);
            p.fsg[b * M + m] = (f - p.rm1[m]) * sc + p.bb1[m];
        }
        // seed out[b] = b2 (before grid.sync; atomics only after)
        if (bid == 0 && tid < B) {
            p.out[tid] = p.b2[0];
        }
    }
    grid.sync();

    // ---------------- Phase C: MLP + final dot (blocks 0..127) ----------------
    if (bid < H / 8) {
        const int i = bid * 8 + w;          // output row 0..1023
        const float* wrow = p.w1 + (size_t)i * M;
        float hsum[B] = {0, 0, 0, 0, 0, 0, 0, 0};
#pragma unroll
        for (int seg = 0; seg < 4; ++seg) {
            int m0 = seg * 256 + lane * 4;
            float4 wv4 = *reinterpret_cast<const float4*>(wrow + m0);
#pragma unroll
            for (int bb = 0; bb < B; ++bb) {
                float4 fv = *reinterpret_cast<const float4*>(&p.fsg[bb * M + m0]);
                hsum[bb] = fmaf(fv.x, wv4.x, hsum[bb]);
                hsum[bb] = fmaf(fv.y, wv4.y, hsum[bb]);
                hsum[bb] = fmaf(fv.z, wv4.z, hsum[bb]);
                hsum[bb] = fmaf(fv.w, wv4.w, hsum[bb]);
            }
        }
#pragma unroll
        for (int bb = 0; bb < B; ++bb) {
#pragma unroll
            for (int off = 32; off > 0; off >>= 1) {
                hsum[bb] += __shfl_down(hsum[bb], off, 64);
            }
        }
        if (lane == 0) {
            float b1i = p.b1[i];
            float sc2 = p.g2[i] * rsqrtf(p.rv2[i] + BN_EPS);
            float rm = p.rm2[i];
            float bt = p.bb2[i];
            float w2i = p.w2[i];
#pragma unroll
            for (int bb = 0; bb < B; ++bb) {
                float v = fmaxf(hsum[bb] + b1i, 0.0f);
                v = (v - rm) * sc2 + bt;
                cpart[w][bb] = v * w2i;
            }
        }
        __syncthreads();
        if (tid < B) {
            float s = 0.0f;
#pragma unroll
            for (int q = 0; q < 8; ++q) s += cpart[q][tid];
            atomicAdd(&p.out[tid], s);
        }
    }
}

// ---------------------------------------------------------------------------
extern "C" void kernel_launch(void* const* d_in, const int* in_sizes, int n_in,
                              void* d_out, int out_size, void* d_ws, size_t ws_size,
                              hipStream_t stream) {
    Params prm;
    prm.x     = (const float*)d_in[0];
    prm.basis = (const float*)d_in[1];
    prm.g1    = (const float*)d_in[2];
    prm.bb1   = (const float*)d_in[3];
    prm.rm1   = (const float*)d_in[4];
    prm.rv1   = (const float*)d_in[5];
    prm.w1    = (const float*)d_in[6];
    prm.b1    = (const float*)d_in[7];
    prm.g2    = (const float*)d_in[8];
    prm.bb2   = (const float*)d_in[9];
    prm.rm2   = (const float*)d_in[10];
    prm.rv2   = (const float*)d_in[11];
    prm.w2    = (const float*)d_in[12];
    prm.b2    = (const float*)d_in[13];
    prm.out   = (float*)d_out;
    prm.fsg   = (float*)d_ws;              // 8*1024 floats

    void* args[] = { &prm };
    hipLaunchCooperativeKernel((const void*)fused_kernel, dim3(256), dim3(512),
                               args, 0, stream);
}